// Round 5
// baseline (23676.418 us; speedup 1.0000x reference)
//
#include <hip/hip_runtime.h>

#define SEQ   2048
#define EMBD  512
#define HID   512
#define NB    32      // batch
#define NSL   128     // WG slices per layer (each owns 4 hidden cols x 4 gates = 16 gate rows)
#define NWG   256
#define NTHR  256
#define POLL_CAP 5000000

typedef __attribute__((ext_vector_type(8))) short bf16x8;
typedef __attribute__((ext_vector_type(4))) float f32x4;

__device__ __forceinline__ float sigf(float x) { return 1.0f / (1.0f + __expf(-x)); }
__device__ __forceinline__ float tanhf_fast(float x) {
    float e = __expf(2.0f * x);
    return (e - 1.0f) / (e + 1.0f);
}
// RNE f32 -> bf16 (bit trick; values here are tame, no NaN handling needed)
__device__ __forceinline__ short f2bf(float f) {
    unsigned u = __float_as_uint(f);
    unsigned r = (u + 0x7FFFu + ((u >> 16) & 1u)) >> 16;
    return (short)r;
}
__device__ __forceinline__ float bf2f(unsigned short s) {
    return __uint_as_float(((unsigned)s) << 16);
}
__device__ __forceinline__ bf16x8 cvt8(float4 a, float4 b) {
    bf16x8 r;
    r[0] = f2bf(a.x); r[1] = f2bf(a.y); r[2] = f2bf(a.z); r[3] = f2bf(a.w);
    r[4] = f2bf(b.x); r[5] = f2bf(b.y); r[6] = f2bf(b.z); r[7] = f2bf(b.w);
    return r;
}

// Relaxed agent-scope atomics (LLC-coherent, no fence, no L1/L2 maintenance).
// Proven rounds 2-4: vmcnt(0)-drained sc1 stores become visible to remote
// relaxed loads in order (absmax 0.0 across 3 passing rounds).
__device__ __forceinline__ unsigned ld_a(const unsigned* p) {
    return __hip_atomic_load((unsigned*)p, __ATOMIC_RELAXED, __HIP_MEMORY_SCOPE_AGENT);
}
__device__ __forceinline__ void st_a(unsigned* p, unsigned v) {
    __hip_atomic_store(p, v, __ATOMIC_RELAXED, __HIP_MEMORY_SCOPE_AGENT);
}
__device__ __forceinline__ bf16x8 ld_h8(const unsigned* p) {
    union { unsigned u[4]; bf16x8 v; } x;
    x.u[0] = ld_a(p + 0); x.u[1] = ld_a(p + 1);
    x.u[2] = ld_a(p + 2); x.u[3] = ld_a(p + 3);
    return x.v;
}

// MFMA half-GEMM on h-state (u32-packed bf16 pairs) -> LDS partials
__device__ __forceinline__ void h_mfma(
    const unsigned* __restrict__ bsrc, const bf16x8* A,
    int kb, int hi, int i16, int w, float (*part)[16][16])
{
    f32x4 acc0 = {0.f, 0.f, 0.f, 0.f};
    f32x4 acc1 = {0.f, 0.f, 0.f, 0.f};
    const unsigned* pb0 = bsrc + (size_t)i16 * (HID / 2);
    const unsigned* pb1 = bsrc + (size_t)(16 + i16) * (HID / 2);
    const int kb2 = kb / 2;
    #pragma unroll
    for (int q = 0; q < 8; ++q) {
        int ko2 = kb2 + q * 16 + hi * 4;
        bf16x8 B0 = ld_h8(pb0 + ko2);
        bf16x8 B1 = ld_h8(pb1 + ko2);
        acc0 = __builtin_amdgcn_mfma_f32_16x16x32_bf16(A[q], B0, acc0, 0, 0, 0);
        acc1 = __builtin_amdgcn_mfma_f32_16x16x32_bf16(A[q], B1, acc1, 0, 0, 0);
    }
    #pragma unroll
    for (int r = 0; r < 4; ++r) {
        part[w * 2 + 0][hi * 4 + r][i16] = acc0[r];
        part[w * 2 + 1][hi * 4 + r][i16] = acc1[r];
    }
}

// Layer-0 x-half (embedding gather) for step tt -> LDS partials.
// h-independent: scheduled UNDER the barrier wait (software pipeline).
__device__ __forceinline__ void l0_x_mfma(
    int tt, const int* __restrict__ tokens, const float* __restrict__ emb,
    const bf16x8* A, int kb, int hi, int i16, int w, float (*part)[16][16])
{
    f32x4 acc0 = {0.f, 0.f, 0.f, 0.f};
    f32x4 acc1 = {0.f, 0.f, 0.f, 0.f};
    const int b0 = i16, b1 = 16 + i16;
    const size_t r0 = (size_t)tokens[b0 * SEQ + tt] * EMBD;
    const size_t r1 = (size_t)tokens[b1 * SEQ + tt] * EMBD;
    #pragma unroll
    for (int q = 0; q < 8; ++q) {
        int koff = kb + q * 32 + hi * 8;
        float4 xa0 = *(const float4*)(emb + r0 + koff);
        float4 xb0 = *(const float4*)(emb + r0 + koff + 4);
        float4 xa1 = *(const float4*)(emb + r1 + koff);
        float4 xb1 = *(const float4*)(emb + r1 + koff + 4);
        bf16x8 B0 = cvt8(xa0, xb0);
        bf16x8 B1 = cvt8(xa1, xb1);
        acc0 = __builtin_amdgcn_mfma_f32_16x16x32_bf16(A[q], B0, acc0, 0, 0, 0);
        acc1 = __builtin_amdgcn_mfma_f32_16x16x32_bf16(A[q], B1, acc1, 0, 0, 0);
    }
    #pragma unroll
    for (int r = 0; r < 4; ++r) {
        part[w * 2 + 0][hi * 4 + r][i16] = acc0[r];
        part[w * 2 + 1][hi * 4 + r][i16] = acc1[r];
    }
}

// Persistent kernel, 256 WGs (1/CU), 2049 phases.
// Phase: [old-data MFMA halves] SYNC [gates + h store + vmcnt + slot store]
//        SYNC [L0: next-step x-half under the wait] [4-wave decentralized
//        slot sweep, 1 slot/lane] SYNC.
__global__ __launch_bounds__(NTHR, 1) void lstm_persist(
    const int*   __restrict__ tokens, const float* __restrict__ emb,
    const float* __restrict__ w_ih,   const float* __restrict__ w_hh,
    const float* __restrict__ b_ih,   const float* __restrict__ b_hh,
    const float* __restrict__ fc_w,   const float* __restrict__ fc_b,
    float* __restrict__ out,
    unsigned* __restrict__ slots, unsigned* __restrict__ hbuf)
{
    __shared__ float part[8][16][16];   // [w*2+ct][m][c]

    const int tid   = threadIdx.x;
    const int wg    = blockIdx.x;
    const bool l1   = (wg >= NSL);
    const int s     = l1 ? (wg - NSL) : wg;
    const int layer = l1 ? 1 : 0;
    const int w     = tid >> 6;       // wave 0..3
    const int lane  = tid & 63;
    const int i16   = lane & 15;      // A row m / B col / C col
    const int hi    = lane >> 4;      // k-group
    const int kb    = (w & 1) * 256;  // k offset within ih- or hh-half
    const bool xw   = (w < 2);        // "input"-half waves

    // u32-packed h buffers: [b][HID/2], 8192 u32 each
    unsigned* const h0a_ = hbuf;
    unsigned* const h0b_ = hbuf + NB * HID / 2;
    unsigned* const h1a_ = hbuf + 2 * NB * HID / 2;
    unsigned* const h1b_ = hbuf + 3 * NB * HID / 2;

    // ---- A fragments (weights) once, kept in registers for the whole run ----
    const int m    = i16;
    const int gg_  = m >> 2, jj_ = m & 3;
    const int rowg = gg_ * 512 + s * 4 + jj_;
    const float* wbase = xw ? (w_ih + ((size_t)layer * 2048 + rowg) * 512)
                            : (w_hh + ((size_t)layer * 2048 + rowg) * 512);
    bf16x8 A[8];
    #pragma unroll
    for (int q = 0; q < 8; ++q) {
        int koff = kb + q * 32 + hi * 8;
        float4 wa = *(const float4*)(wbase + koff);
        float4 wb = *(const float4*)(wbase + koff + 4);
        A[q] = cvt8(wa, wb);
    }

    // ---- per-thread cell state: threads 0..63 own (pr, eb), 2 hidden cols ----
    const int eb  = tid & 31;
    const int pr  = tid >> 5;          // valid for tid<64
    const int ect = eb >> 4, ec = eb & 15;
    float cA = 0.0f, cB = 0.0f;
    float biasA[4] = {0.f,0.f,0.f,0.f}, biasB[4] = {0.f,0.f,0.f,0.f};
    if (tid < 64) {
        #pragma unroll
        for (int g = 0; g < 4; ++g) {
            int rg = g * 512 + s * 4 + pr * 2;
            biasA[g] = b_ih[layer * 2048 + rg]     + b_hh[layer * 2048 + rg];
            biasB[g] = b_ih[layer * 2048 + rg + 1] + b_hh[layer * 2048 + rg + 1];
        }
    }

    bool broken = false;
    int polls = 0;

    // ---- prologue: L0 x-half for t=0 (part slots 0..3) ----
    if (!l1 && xw) l0_x_mfma(0, tokens, emb, A, kb, hi, i16, w, part);

    for (int k = 0; k <= SEQ; ++k) {
        const int t = l1 ? (k - 1) : k;
        const bool active = (t >= 0 && t < SEQ);
        const int p = t & 1;

        // ---- step 1: MFMA halves whose inputs were confirmed last phase ----
        if (active) {
            if (!l1) {
                if (!xw) {
                    const unsigned* h0pp = p ? h0a_ : h0b_;   // h0[t-1]
                    h_mfma(h0pp, A, kb, hi, i16, w, part);
                }
                // xw waves: part[0..3] already written (prologue / prior step 5)
            } else {
                const unsigned* bsrc = xw ? (p ? h0b_ : h0a_)    // h0[t]
                                          : (p ? h1a_ : h1b_);   // h1[t-1]
                h_mfma(bsrc, A, kb, hi, i16, w, part);
            }
        }
        __syncthreads();   // SYNC_A: all partials for step t in LDS

        // ---- step 3: gates + cell update + h store (wave 0), then slot ----
        if (active && tid < 64) {
            float gA[4], gB[4];
            #pragma unroll
            for (int g = 0; g < 4; ++g) {
                int mm = g * 4 + pr * 2;
                gA[g] = part[0 + ect][mm][ec]     + part[2 + ect][mm][ec]
                      + part[4 + ect][mm][ec]     + part[6 + ect][mm][ec]     + biasA[g];
                gB[g] = part[0 + ect][mm + 1][ec] + part[2 + ect][mm + 1][ec]
                      + part[4 + ect][mm + 1][ec] + part[6 + ect][mm + 1][ec] + biasB[g];
            }
            // gate order: i, f, g, o
            cA = sigf(gA[1]) * cA + sigf(gA[0]) * tanhf_fast(gA[2]);
            float hA = sigf(gA[3]) * tanhf_fast(cA);
            cB = sigf(gB[1]) * cB + sigf(gB[0]) * tanhf_fast(gB[2]);
            float hB = sigf(gB[3]) * tanhf_fast(cB);
            unsigned val = (unsigned)(unsigned short)f2bf(hA)
                         | ((unsigned)(unsigned short)f2bf(hB) << 16);
            unsigned* hout = l1 ? (p ? h1b_ : h1a_) : (p ? h0b_ : h0a_);
            st_a(hout + eb * (HID / 2) + s * 2 + pr, val);
        }
        if (tid == 0) {
            // drain wave-0's h stores to the LLC, then publish arrival
            asm volatile("s_waitcnt vmcnt(0)" ::: "memory");
            st_a(&slots[wg * 32], (unsigned)(k + 1));
        }
        __syncthreads();   // SYNC_C: gate reads done; part[] free to overwrite

        // ---- step 5: L0 x-half for t+1, hidden under the barrier wait ----
        if (!l1 && xw && (t + 1) < SEQ)
            l0_x_mfma(t + 1, tokens, emb, A, kb, hi, i16, w, part);

        // ---- step 6: decentralized sweep — each wave owns a 64-slot quarter ----
        {
            const unsigned target = (unsigned)(k + 1);
            const unsigned* myslot = &slots[(unsigned)(w * 64 + lane) * 32];
            for (;;) {
                if (broken) break;
                unsigned v = ld_a(myslot);
                if (__all(v >= target)) break;
                __builtin_amdgcn_s_sleep(1);
                if (++polls > POLL_CAP) broken = true;   // bailout: never hang
            }
        }
        __syncthreads();   // SYNC_D: all 256 WGs arrived; fresh h visible
    }

    // ---- FC head: WG 0. h1 final (t=2047, parity 1) -> h1b ----
    if (wg == 0 && tid < 64) {
        const int b = tid >> 1, o = tid & 1;
        float acc = 0.f;
        for (int j2 = 0; j2 < HID / 2; ++j2) {
            unsigned u = ld_a(h1b_ + b * (HID / 2) + j2);
            acc += bf2f((unsigned short)(u & 0xFFFFu)) * fc_w[o * HID + 2 * j2]
                 + bf2f((unsigned short)(u >> 16))     * fc_w[o * HID + 2 * j2 + 1];
        }
        out[b * 2 + o] = sigf(acc + fc_b[o]);
    }
}

extern "C" void kernel_launch(void* const* d_in, const int* in_sizes, int n_in,
                              void* d_out, int out_size, void* d_ws, size_t ws_size,
                              hipStream_t stream)
{
    const int*   tokens = (const int*)d_in[0];
    const float* emb    = (const float*)d_in[1];
    const float* w_ih   = (const float*)d_in[2];
    const float* w_hh   = (const float*)d_in[3];
    const float* b_ih   = (const float*)d_in[4];
    const float* b_hh   = (const float*)d_in[5];
    const float* fc_w   = (const float*)d_in[6];
    const float* fc_b   = (const float*)d_in[7];

    unsigned* slots = (unsigned*)((char*)d_ws + 256);   // slot[wg] at wg*128B
    unsigned* hbuf  = (unsigned*)((char*)d_ws + 65536); // 4 x 8192 u32

    // zero slots + the 4 h buffers (h[-1] = 0); c lives in registers
    hipMemsetAsync(d_ws, 0, 65536 + (size_t)4 * NB * (HID / 2) * sizeof(unsigned), stream);

    lstm_persist<<<dim3(NWG), dim3(NTHR), 0, stream>>>(
        tokens, emb, w_ih, w_hh, b_ih, b_hh, fc_w, fc_b,
        (float*)d_out, slots, hbuf);
}